// Round 7
// baseline (459.161 us; speedup 1.0000x reference)
//
#include <hip/hip_runtime.h>

// RecallK via bf16 hi/lo split on matrix cores.
// dot(x_i,x_j) = hi.hi + hi.lo + lo.hi + lo.lo; argmin_j (sq_j - 2*dot) per row.
// R7: de-lockstep. R6 (1 block/CU, 8 lockstep waves) measured MfmaUtil 41% — barrier
// phases align all waves, so the matrix pipe idles during every epilogue/stage phase.
// Now: LDS 64 KB (64-col B tile, hi+lo, dbuf) -> 2 independent blocks/CU -> block A's
// epilogue overlaps block B's MFMA; 4 waves/SIMD. Block = 8 waves x 32 rows = 256 rows,
// all waves share the 64 cols (no cross-wave col merge). Grid = 64 panels x 8 slices;
// slice = bid&7 pins one 1 MB B-slice per XCD (L2-resident).
// P layout (A and B frags of mfma_f32_32x32x16_bf16 read lane-linear 16B chunks):
//   chunk(g,ks,kh,c) = ((g*8+ks)*2+kh)*32 + c   holds  X[g*32+c][ks*16+kh*8 .. +8]
//   frag lane l -> kh = l>>5, c = l&31 -> lds/global addr = base + l*16 (conflict-free)

typedef __bf16 bf16x8 __attribute__((ext_vector_type(8)));
typedef float f32x16 __attribute__((ext_vector_type(16)));

#define NN 16384
#define MFMA(A, B, C) __builtin_amdgcn_mfma_f32_32x32x16_bf16(A, B, C, 0, 0, 0)
#define GLDS(gsrc, ldst)                                                              \
  __builtin_amdgcn_global_load_lds((const __attribute__((address_space(1))) void*)(gsrc), \
                                   (__attribute__((address_space(3))) void*)(ldst), 16, 0, 0)

// --- per-row squared norms, exact fp32 (one wave per row) ---
__global__ __launch_bounds__(256) void sq_kernel(const float* __restrict__ feat,
                                                 float* __restrict__ sq) {
  int gid = blockIdx.x * 256 + threadIdx.x;
  int row = gid >> 6;
  int lane = threadIdx.x & 63;
  float2 v = reinterpret_cast<const float2*>(feat + (size_t)row * 128)[lane];
  float s = v.x * v.x + v.y * v.y;
#pragma unroll
  for (int off = 32; off > 0; off >>= 1) s += __shfl_xor(s, off, 64);
  if (lane == 0) sq[row] = s;
}

// --- fp32 -> (hi,lo) bf16 banks in MFMA-chunk-permuted order ---
__global__ __launch_bounds__(256) void convert_kernel(const float* __restrict__ feat,
                                                      bf16x8* __restrict__ Ph,
                                                      bf16x8* __restrict__ Pl) {
  int chunk = blockIdx.x * 256 + threadIdx.x;  // 262144 chunks
  int c = chunk & 31;
  int kh = (chunk >> 5) & 1;
  int ks = (chunk >> 6) & 7;
  int g = chunk >> 9;
  int row = g * 32 + c;
  int k0 = ks * 16 + kh * 8;
  const float4* s = reinterpret_cast<const float4*>(feat + (size_t)row * 128 + k0);
  float4 v0 = s[0], v1 = s[1];
  float xs[8] = {v0.x, v0.y, v0.z, v0.w, v1.x, v1.y, v1.z, v1.w};
  bf16x8 hv, lv;
#pragma unroll
  for (int e = 0; e < 8; ++e) {
    float x = xs[e];
    __bf16 h = (__bf16)x;
    hv[e] = h;
    lv[e] = (__bf16)(x - (float)h);
  }
  Ph[chunk] = hv;
  Pl[chunk] = lv;
}

// --- main: 512 blocks (64 row-panels x 8 col-slices), 8 waves x 32 rows, 64-col tiles ---
__global__ __launch_bounds__(512, 4) void nn_mfma(const bf16x8* __restrict__ Ph,
                                                  const bf16x8* __restrict__ Pl,
                                                  const float* __restrict__ sq,
                                                  float* __restrict__ bestD,
                                                  int* __restrict__ bestI) {
  __shared__ bf16x8 BhL[2][1024];  // 2 buf x (2 cg x 8 ks x 64 lanes) = 32 KB
  __shared__ bf16x8 BlL[2][1024];  // 32 KB  -> total 64 KB -> 2 blocks/CU
  const int bid = blockIdx.x;
  const int slice = bid & 7;       // one 2048-col slice per XCD (1 MB, L2-resident)
  const int panel = bid >> 3;      // 0..63 row-panels of 256 rows
  const int tid = threadIdx.x;
  const int w = tid >> 6;          // wave 0..7
  const int lane = tid & 63;
  const int laneh = lane >> 5, lanec = lane & 31;

  // A row-group (32 rows x K=128, hi+lo) into registers: 16 frags = 64 VGPR
  bf16x8 Ah[8], Al[8];
  {
    int g = panel * 8 + w;
#pragma unroll
    for (int ks = 0; ks < 8; ++ks) {
      int ch = ((g * 8 + ks) * 2 + laneh) * 32 + lanec;
      Ah[ks] = Ph[ch];
      Al[ks] = Pl[ch];
    }
  }

  // stage one 64-col B tile (hi+lo) into buffer `nbuf`: 32 GLDS total, 4 per wave.
  // wave w: bank = w&1, col-group = (w>>1)&1, ks-quad = w>>2
  auto stage = [&](int nbuf, int tt) {
    const int cgi = (w >> 1) & 1;
    const int gcol = slice * 64 + tt * 2 + cgi;
    const int ks0 = (w >> 2) * 4;
    const bf16x8* src = (w & 1) ? Pl : Ph;
    bf16x8* dst = (w & 1) ? &BlL[nbuf][cgi * 512] : &BhL[nbuf][cgi * 512];
#pragma unroll
    for (int ks = ks0; ks < ks0 + 4; ++ks) {
      size_t srcoff = ((size_t)((gcol * 8 + ks) * 64 + lane)) * 16;
      GLDS((const char*)src + srcoff, dst + ks * 64);
    }
  };

  float bD0[16], bD1[16];
  int bI0[16], bI1[16];
#pragma unroll
  for (int r = 0; r < 16; ++r) {
    bD0[r] = 3.4e38f; bD1[r] = 3.4e38f;
    bI0[r] = 0; bI1[r] = 0;
  }

  stage(0, 0);
  __syncthreads();  // full fence: stage complete + all waves synced

  int buf = 0;
  const int igbase = panel * 256 + w * 32 + 4 * laneh;

  for (int t = 0; t < 32; ++t) {
    const int jb = slice * 2048 + t * 64;
    const int j0 = jb + lanec;
    const int j1 = j0 + 32;
    float sq0 = sq[j0];   // issued before stage: compiler wait = counted vmcnt
    float sq1 = sq[j1];
    if (t < 31) stage(buf ^ 1, t + 1);

    f32x16 a0 = {}, a1 = {};
#pragma unroll
    for (int ks = 0; ks < 8; ++ks) {
      bf16x8 b0h = BhL[buf][ks * 64 + lane];
      bf16x8 b0l = BlL[buf][ks * 64 + lane];
      bf16x8 b1h = BhL[buf][512 + ks * 64 + lane];
      bf16x8 b1l = BlL[buf][512 + ks * 64 + lane];
      a0 = MFMA(Ah[ks], b0h, a0);
      a0 = MFMA(Al[ks], b0h, a0);
      a0 = MFMA(Ah[ks], b0l, a0);
      a0 = MFMA(Al[ks], b0l, a0);
      a1 = MFMA(Ah[ks], b1h, a1);
      a1 = MFMA(Al[ks], b1h, a1);
      a1 = MFMA(Ah[ks], b1l, a1);
      a1 = MFMA(Al[ks], b1l, a1);
    }

    // epilogue: d = sq_j - 2*dot; strict < + ascending t keeps earliest j per array
#pragma unroll
    for (int r = 0; r < 16; ++r) {
      int rb = (r & 3) + 8 * (r >> 2);
      int ig = igbase + rb;
      {
        float d = fmaf(-2.0f, a0[r], sq0);
        if (j0 != ig && d < bD0[r]) { bD0[r] = d; bI0[r] = j0; }
      }
      {
        float d = fmaf(-2.0f, a1[r], sq1);
        if (j1 != ig && d < bD1[r]) { bD1[r] = d; bI1[r] = j1; }
      }
    }

    __syncthreads();  // drains my stage (vmcnt 0) + all waves done reading buf
    buf ^= 1;
  }

  // merge the two col-sets, then cross-lane argmin over the 32 lanec lanes;
  // lexicographic (d, j) everywhere = numpy first-min. Rows are wave-exclusive.
#pragma unroll
  for (int r = 0; r < 16; ++r) {
    float d0 = bD0[r];
    int i0 = bI0[r];
    if (bD1[r] < d0 || (bD1[r] == d0 && bI1[r] < i0)) { d0 = bD1[r]; i0 = bI1[r]; }
#pragma unroll
    for (int off = 1; off < 32; off <<= 1) {
      float od = __shfl_xor(d0, off);
      int oi = __shfl_xor(i0, off);
      if (od < d0 || (od == d0 && oi < i0)) { d0 = od; i0 = oi; }
    }
    if (lanec == 0) {
      int row = igbase + (r & 3) + 8 * (r >> 2);
      bestD[slice * NN + row] = d0;
      bestI[slice * NN + row] = i0;
    }
  }
}

// --- merge 8 slices per row, count label matches ---
__global__ __launch_bounds__(256) void combine_kernel(const float* __restrict__ bestD,
                                                      const int* __restrict__ bestI,
                                                      const int* __restrict__ labels,
                                                      int* __restrict__ count) {
  int r = blockIdx.x * 256 + threadIdx.x;
  float d = bestD[r];
  int i = bestI[r];
#pragma unroll
  for (int s = 1; s < 8; ++s) {
    float ds = bestD[s * NN + r];
    int is = bestI[s * NN + r];
    if (ds < d || (ds == d && is < i)) { d = ds; i = is; }
  }
  bool match = (labels[i] == labels[r]);
  unsigned long long mb = __ballot(match);
  if ((threadIdx.x & 63) == 0) atomicAdd(count, (int)__popcll(mb));
}

__global__ void finalize_kernel(const int* __restrict__ count, float* __restrict__ out) {
  out[0] = (float)(*count) * (1.0f / 16384.0f);
}

extern "C" void kernel_launch(void* const* d_in, const int* in_sizes, int n_in,
                              void* d_out, int out_size, void* d_ws, size_t ws_size,
                              hipStream_t stream) {
  const float* feat = (const float*)d_in[0];
  const int* labels = (const int*)d_in[1];
  float* out = (float*)d_out;
  char* ws = (char*)d_ws;

  int* count = (int*)ws;                              // 4 B
  float* sq = (float*)(ws + 1024);                    // 64 KB
  float* bestD = (float*)(ws + (1 << 19));            // 8*N floats = 512 KB
  int* bestI = (int*)(ws + (1 << 20));                // 8*N ints  = 512 KB
  bf16x8* Ph = (bf16x8*)(ws + (2 << 20));             // 4 MB
  bf16x8* Pl = (bf16x8*)(ws + (6 << 20));             // 4 MB   (total 10 MB)

  hipMemsetAsync(count, 0, sizeof(int), stream);
  sq_kernel<<<NN / 4, 256, 0, stream>>>(feat, sq);
  convert_kernel<<<1024, 256, 0, stream>>>(feat, Ph, Pl);
  nn_mfma<<<512, 512, 0, stream>>>(Ph, Pl, sq, bestD, bestI);
  combine_kernel<<<NN / 256, 256, 0, stream>>>(bestD, bestI, labels, count);
  finalize_kernel<<<1, 1, 0, stream>>>(count, out);
}

// Round 8
// 230.138 us; speedup vs baseline: 1.9952x; 1.9952x over previous
//
#include <hip/hip_runtime.h>

// RecallK via bf16 hi/lo split on matrix cores.
// dot(x_i,x_j) = hi.hi + hi.lo + lo.hi + lo.lo; argmin_j (sq_j - 2*dot) per row.
// R8: de-lockstep WITH a register budget. R7's launch_bounds(512,4) spilled (needs
// ~190 VGPR > 128 cap -> 588 MB scratch writes, 457us). Redesign for ~105 VGPR:
// 16-row waves + mfma_f32_16x16x32_bf16 (A hi+lo = 32 VGPR), 2x f32x4 acc chains,
// merged best/bidx[4]. LDS 64 KB -> 2 blocks/CU -> 4 waves/SIMD: cross-block overlap
// of epilogue/stage phases with MFMA phases (m114). 16x16 pipe is ~13% slower than
// 32x32 (floor 132us vs 109us) — price of fitting 128 VGPR.
// P16 layout (A and B frags of mfma_f32_16x16x32_bf16 read lane-linear 16B chunks):
//   chunk(g16,ks,l) = (g16*4+ks)*64+l  holds  X[g16*16+(l&15)][ks*32+(l>>4)*8 .. +8]
//   same permutation for A and B -> any within-k shuffle cancels in A.B

typedef __bf16 bf16x8 __attribute__((ext_vector_type(8)));
typedef float f32x4 __attribute__((ext_vector_type(4)));

#define NN 16384
#define MFMA16(A, B, C) __builtin_amdgcn_mfma_f32_16x16x32_bf16(A, B, C, 0, 0, 0)
#define GLDS(gsrc, ldst)                                                              \
  __builtin_amdgcn_global_load_lds((const __attribute__((address_space(1))) void*)(gsrc), \
                                   (__attribute__((address_space(3))) void*)(ldst), 16, 0, 0)

// --- per-row squared norms, exact fp32 (one wave per row) ---
__global__ __launch_bounds__(256) void sq_kernel(const float* __restrict__ feat,
                                                 float* __restrict__ sq) {
  int gid = blockIdx.x * 256 + threadIdx.x;
  int row = gid >> 6;
  int lane = threadIdx.x & 63;
  float2 v = reinterpret_cast<const float2*>(feat + (size_t)row * 128)[lane];
  float s = v.x * v.x + v.y * v.y;
#pragma unroll
  for (int off = 32; off > 0; off >>= 1) s += __shfl_xor(s, off, 64);
  if (lane == 0) sq[row] = s;
}

// --- fp32 -> (hi,lo) bf16 banks in 16-row-group MFMA-chunk order ---
__global__ __launch_bounds__(256) void convert_kernel(const float* __restrict__ feat,
                                                      bf16x8* __restrict__ Ph,
                                                      bf16x8* __restrict__ Pl) {
  int chunk = blockIdx.x * 256 + threadIdx.x;  // 262144 chunks
  int l = chunk & 63;
  int ks = (chunk >> 6) & 3;
  int g = chunk >> 8;                          // 0..1023 (16-row groups)
  int row = g * 16 + (l & 15);
  int k0 = ks * 32 + (l >> 4) * 8;
  const float4* s = reinterpret_cast<const float4*>(feat + (size_t)row * 128 + k0);
  float4 v0 = s[0], v1 = s[1];
  float xs[8] = {v0.x, v0.y, v0.z, v0.w, v1.x, v1.y, v1.z, v1.w};
  bf16x8 hv, lv;
#pragma unroll
  for (int e = 0; e < 8; ++e) {
    float x = xs[e];
    __bf16 h = (__bf16)x;
    hv[e] = h;
    lv[e] = (__bf16)(x - (float)h);
  }
  Ph[chunk] = hv;
  Pl[chunk] = lv;
}

// --- main: 512 blocks (128 panels x 4 slices), 8 waves x 16 rows, 64-col tiles ---
__global__ __launch_bounds__(512, 4) void nn_mfma(const bf16x8* __restrict__ Ph,
                                                  const bf16x8* __restrict__ Pl,
                                                  const float* __restrict__ sq,
                                                  float* __restrict__ bestD,
                                                  int* __restrict__ bestI) {
  __shared__ bf16x8 BhL[2][1024];  // [buf][cgi*256 + ks*64 + lane]  2 x 16 KB
  __shared__ bf16x8 BlL[2][1024];  // 2 x 16 KB  -> total 64 KB -> 2 blocks/CU
  const int bid = blockIdx.x;
  const int slice = bid & 3;       // 4096-col slice; xcd=bid&7 -> one slice per XCD (2 MB, L2-fit)
  const int panel = bid >> 2;      // 0..127 row-panels of 128 rows
  const int tid = threadIdx.x;
  const int w = tid >> 6;          // wave 0..7
  const int lane = tid & 63;
  const int lq = lane >> 4;        // k-quarter / row-quad selector
  const int lc = lane & 15;        // col-in-group

  // A row-group (16 rows x K=128, hi+lo): 8 frags = 32 VGPR
  bf16x8 Ah[4], Al[4];
  {
    int gA = panel * 8 + w;
#pragma unroll
    for (int ks = 0; ks < 4; ++ks) {
      int ch = (gA * 4 + ks) * 64 + lane;
      Ah[ks] = Ph[ch];
      Al[ks] = Pl[ch];
    }
  }

  // stage one 64-col B tile (hi+lo) into buffer `nbuf`: 32 GLDS, 4 per wave.
  // wave w: bank = w&1, col-16-group cgi = w>>1
  auto stage = [&](int nbuf, int tt) {
    const int cgi = w >> 1;
    const int gcol = slice * 256 + tt * 4 + cgi;
    const bf16x8* src = (w & 1) ? Pl : Ph;
    bf16x8* dst = ((w & 1) ? &BlL[nbuf][0] : &BhL[nbuf][0]) + cgi * 256;
#pragma unroll
    for (int ks = 0; ks < 4; ++ks) {
      size_t srcoff = ((size_t)((gcol * 4 + ks) * 64 + lane)) * 16;
      GLDS((const char*)src + srcoff, dst + ks * 64);
    }
  };

  float best[4];
  int bidx[4];
#pragma unroll
  for (int r = 0; r < 4; ++r) {
    best[r] = 3.4e38f;
    bidx[r] = 0;
  }

  stage(0, 0);
  __syncthreads();  // full fence: stage complete + all waves synced

  int buf = 0;
  const int igbase = panel * 128 + w * 16 + lq * 4;  // + r = this lane's C rows

  for (int t = 0; t < 64; ++t) {
    const int jb = slice * 4096 + t * 64;
    float sqc[4];
#pragma unroll
    for (int cg = 0; cg < 4; ++cg) sqc[cg] = sq[jb + cg * 16 + lc];  // before stage:
    if (t < 63) stage(buf ^ 1, t + 1);                               // counted vmcnt wait

    // two concurrent 16-col acc chains per pair, 64 MFMA/tile
#pragma unroll
    for (int cp = 0; cp < 2; ++cp) {
      const int cg0 = cp * 2, cg1 = cp * 2 + 1;
      f32x4 a0 = {}, a1 = {};
#pragma unroll
      for (int ks = 0; ks < 4; ++ks) {
        bf16x8 b0h = BhL[buf][cg0 * 256 + ks * 64 + lane];
        bf16x8 b0l = BlL[buf][cg0 * 256 + ks * 64 + lane];
        bf16x8 b1h = BhL[buf][cg1 * 256 + ks * 64 + lane];
        bf16x8 b1l = BlL[buf][cg1 * 256 + ks * 64 + lane];
        a0 = MFMA16(Ah[ks], b0h, a0);
        a0 = MFMA16(Al[ks], b0h, a0);
        a0 = MFMA16(Ah[ks], b0l, a0);
        a0 = MFMA16(Al[ks], b0l, a0);
        a1 = MFMA16(Ah[ks], b1h, a1);
        a1 = MFMA16(Al[ks], b1h, a1);
        a1 = MFMA16(Ah[ks], b1l, a1);
        a1 = MFMA16(Al[ks], b1l, a1);
      }
      // epilogue: d = sq_j - 2*dot; ascending cg then t, strict < = first-min
      const int j0 = jb + cg0 * 16 + lc;
      const int j1 = jb + cg1 * 16 + lc;
#pragma unroll
      for (int r = 0; r < 4; ++r) {
        int ig = igbase + r;
        float d0 = fmaf(-2.0f, a0[r], sqc[cg0]);
        if (j0 != ig && d0 < best[r]) { best[r] = d0; bidx[r] = j0; }
        float d1 = fmaf(-2.0f, a1[r], sqc[cg1]);
        if (j1 != ig && d1 < best[r]) { best[r] = d1; bidx[r] = j1; }
      }
    }

    __syncthreads();  // drains my stage (vmcnt 0) + all waves done reading buf
    buf ^= 1;
  }

  // cross-lane argmin over the 16 col-lanes sharing each row; lex (d,j) = first-min
#pragma unroll
  for (int r = 0; r < 4; ++r) {
    float d = best[r];
    int i = bidx[r];
#pragma unroll
    for (int off = 1; off < 16; off <<= 1) {
      float od = __shfl_xor(d, off);
      int oi = __shfl_xor(i, off);
      if (od < d || (od == d && oi < i)) { d = od; i = oi; }
    }
    if (lc == 0) {
      int row = igbase + r;  // rows are wave- and lane-quad-exclusive
      bestD[slice * NN + row] = d;
      bestI[slice * NN + row] = i;
    }
  }
}

// --- merge 4 slices per row, count label matches ---
__global__ __launch_bounds__(256) void combine_kernel(const float* __restrict__ bestD,
                                                      const int* __restrict__ bestI,
                                                      const int* __restrict__ labels,
                                                      int* __restrict__ count) {
  int r = blockIdx.x * 256 + threadIdx.x;
  float d = bestD[r];
  int i = bestI[r];
#pragma unroll
  for (int s = 1; s < 4; ++s) {
    float ds = bestD[s * NN + r];
    int is = bestI[s * NN + r];
    if (ds < d || (ds == d && is < i)) { d = ds; i = is; }
  }
  bool match = (labels[i] == labels[r]);
  unsigned long long mb = __ballot(match);
  if ((threadIdx.x & 63) == 0) atomicAdd(count, (int)__popcll(mb));
}

__global__ void finalize_kernel(const int* __restrict__ count, float* __restrict__ out) {
  out[0] = (float)(*count) * (1.0f / 16384.0f);
}

extern "C" void kernel_launch(void* const* d_in, const int* in_sizes, int n_in,
                              void* d_out, int out_size, void* d_ws, size_t ws_size,
                              hipStream_t stream) {
  const float* feat = (const float*)d_in[0];
  const int* labels = (const int*)d_in[1];
  float* out = (float*)d_out;
  char* ws = (char*)d_ws;

  int* count = (int*)ws;                              // 4 B
  float* sq = (float*)(ws + 1024);                    // 64 KB
  float* bestD = (float*)(ws + (1 << 19));            // 4*N floats = 256 KB
  int* bestI = (int*)(ws + (1 << 19) + (1 << 18));    // 4*N ints  = 256 KB
  bf16x8* Ph = (bf16x8*)(ws + (2 << 20));             // 4 MB
  bf16x8* Pl = (bf16x8*)(ws + (6 << 20));             // 4 MB   (total 10 MB)

  hipMemsetAsync(count, 0, sizeof(int), stream);
  sq_kernel<<<NN / 4, 256, 0, stream>>>(feat, sq);
  convert_kernel<<<1024, 256, 0, stream>>>(feat, Ph, Pl);
  nn_mfma<<<512, 512, 0, stream>>>(Ph, Pl, sq, bestD, bestI);
  combine_kernel<<<NN / 256, 256, 0, stream>>>(bestD, bestI, labels, count);
  finalize_kernel<<<1, 1, 0, stream>>>(count, out);
}

// Round 9
// 177.599 us; speedup vs baseline: 2.5854x; 1.2958x over previous
//
#include <hip/hip_runtime.h>

// RecallK via bf16 hi/lo split on matrix cores.
// dot(x_i,x_j) ~= hi.hi + lo.hi + hi.lo  (lo.lo dropped: adds ~2e-5 distance noise,
// ~0.2 expected argmin flips vs 3.2-flip threshold budget).
// argmin_j (sq_j - 2*dot) per row == argmin of ref distmat (row-constant sq_i dropped).
// R9: raise MFMA:LDS ratio. R8 (16-row waves, 4 terms) = MfmaUtil 57%: per block-tile
// LDS feed (2048 cyc/CU) ~ MFMA (2483 cyc/CU). Now 32-row waves (A hi+lo = 64 VGPR,
// 2x B-reuse per ds_read) + 3 terms: MFMA floor 99us, LDS 62us, 32 tiles/block.
// VGPR budget ~96 <= 128 keeps 4 waves/SIMD (2 blocks/CU x 8 waves, 64 KB LDS).
// P16 layout (A and B frags of mfma_f32_16x16x32_bf16 read lane-linear 16B chunks):
//   chunk(g16,ks,l) = (g16*4+ks)*64+l  holds  X[g16*16+(l&15)][ks*32+(l>>4)*8 .. +8]
//   same permutation for A and B -> any within-k shuffle cancels in A.B

typedef __bf16 bf16x8 __attribute__((ext_vector_type(8)));
typedef float f32x4 __attribute__((ext_vector_type(4)));

#define NN 16384
#define MFMA16(A, B, C) __builtin_amdgcn_mfma_f32_16x16x32_bf16(A, B, C, 0, 0, 0)
#define GLDS(gsrc, ldst)                                                              \
  __builtin_amdgcn_global_load_lds((const __attribute__((address_space(1))) void*)(gsrc), \
                                   (__attribute__((address_space(3))) void*)(ldst), 16, 0, 0)

// --- per-row squared norms, exact fp32 (one wave per row) ---
__global__ __launch_bounds__(256) void sq_kernel(const float* __restrict__ feat,
                                                 float* __restrict__ sq) {
  int gid = blockIdx.x * 256 + threadIdx.x;
  int row = gid >> 6;
  int lane = threadIdx.x & 63;
  float2 v = reinterpret_cast<const float2*>(feat + (size_t)row * 128)[lane];
  float s = v.x * v.x + v.y * v.y;
#pragma unroll
  for (int off = 32; off > 0; off >>= 1) s += __shfl_xor(s, off, 64);
  if (lane == 0) sq[row] = s;
}

// --- fp32 -> (hi,lo) bf16 banks in 16-row-group MFMA-chunk order ---
__global__ __launch_bounds__(256) void convert_kernel(const float* __restrict__ feat,
                                                      bf16x8* __restrict__ Ph,
                                                      bf16x8* __restrict__ Pl) {
  int chunk = blockIdx.x * 256 + threadIdx.x;  // 262144 chunks
  int l = chunk & 63;
  int ks = (chunk >> 6) & 3;
  int g = chunk >> 8;                          // 0..1023 (16-row groups)
  int row = g * 16 + (l & 15);
  int k0 = ks * 32 + (l >> 4) * 8;
  const float4* s = reinterpret_cast<const float4*>(feat + (size_t)row * 128 + k0);
  float4 v0 = s[0], v1 = s[1];
  float xs[8] = {v0.x, v0.y, v0.z, v0.w, v1.x, v1.y, v1.z, v1.w};
  bf16x8 hv, lv;
#pragma unroll
  for (int e = 0; e < 8; ++e) {
    float x = xs[e];
    __bf16 h = (__bf16)x;
    hv[e] = h;
    lv[e] = (__bf16)(x - (float)h);
  }
  Ph[chunk] = hv;
  Pl[chunk] = lv;
}

// --- main: 512 blocks (64 panels x 8 slices), 8 waves x 32 rows, 64-col tiles ---
__global__ __launch_bounds__(512, 4) void nn_mfma(const bf16x8* __restrict__ Ph,
                                                  const bf16x8* __restrict__ Pl,
                                                  const float* __restrict__ sq,
                                                  float* __restrict__ bestD,
                                                  int* __restrict__ bestI) {
  __shared__ bf16x8 BhL[2][1024];  // [buf][cg*256 + ks*64 + lane]  2 x 16 KB
  __shared__ bf16x8 BlL[2][1024];  // 2 x 16 KB  -> total 64 KB -> 2 blocks/CU
  const int bid = blockIdx.x;
  const int slice = bid & 7;       // 2048-col slice; one per XCD (1 MB hi+lo, L2-fit)
  const int panel = bid >> 3;      // 0..63 row-panels of 256 rows
  const int tid = threadIdx.x;
  const int w = tid >> 6;          // wave 0..7
  const int lane = tid & 63;
  const int lq = lane >> 4;        // row-quad selector in C layout
  const int lc = lane & 15;        // col-in-group

  // A: two 16-row groups (32 rows x K=128, hi+lo): 16 frags = 64 VGPR
  bf16x8 Ah0[4], Al0[4], Ah1[4], Al1[4];
  {
    int gA = panel * 16 + w * 2;
#pragma unroll
    for (int ks = 0; ks < 4; ++ks) {
      Ah0[ks] = Ph[(gA * 4 + ks) * 64 + lane];
      Al0[ks] = Pl[(gA * 4 + ks) * 64 + lane];
      Ah1[ks] = Ph[((gA + 1) * 4 + ks) * 64 + lane];
      Al1[ks] = Pl[((gA + 1) * 4 + ks) * 64 + lane];
    }
  }

  // stage one 64-col B tile (hi+lo) into buffer `nbuf`: 32 GLDS, 4 per wave.
  // wave w: bank = w&1, col-16-group cgi = w>>1
  auto stage = [&](int nbuf, int tt) {
    const int cgi = w >> 1;
    const int gcol = slice * 128 + tt * 4 + cgi;
    const bf16x8* src = (w & 1) ? Pl : Ph;
    bf16x8* dst = ((w & 1) ? &BlL[nbuf][0] : &BhL[nbuf][0]) + cgi * 256;
#pragma unroll
    for (int ks = 0; ks < 4; ++ks) {
      size_t srcoff = ((size_t)((gcol * 4 + ks) * 64 + lane)) * 16;
      GLDS((const char*)src + srcoff, dst + ks * 64);
    }
  };

  float best0[4], best1[4];
  int bidx0[4], bidx1[4];
#pragma unroll
  for (int r = 0; r < 4; ++r) {
    best0[r] = 3.4e38f; best1[r] = 3.4e38f;
    bidx0[r] = 0; bidx1[r] = 0;
  }

  stage(0, 0);
  __syncthreads();  // full fence: stage complete + all waves synced

  int buf = 0;
  const int ig0 = panel * 256 + w * 32 + lq * 4;  // + r = rowgroup0 rows; +16 = rowgroup1

  for (int t = 0; t < 32; ++t) {
    const int jb = slice * 2048 + t * 64;
    float sqc[4];
#pragma unroll
    for (int cg = 0; cg < 4; ++cg) sqc[cg] = sq[jb + cg * 16 + lc];  // before stage:
    if (t < 31) stage(buf ^ 1, t + 1);                               // counted vmcnt wait

    // per cg: 2 ds_reads feed 6 MFMA (2 rowgroups x 3 terms)
#pragma unroll
    for (int cg = 0; cg < 4; ++cg) {
      f32x4 a0 = {}, a1 = {};
#pragma unroll
      for (int ks = 0; ks < 4; ++ks) {
        bf16x8 bh = BhL[buf][cg * 256 + ks * 64 + lane];
        bf16x8 bl = BlL[buf][cg * 256 + ks * 64 + lane];
        a0 = MFMA16(Ah0[ks], bh, a0);
        a0 = MFMA16(Al0[ks], bh, a0);
        a0 = MFMA16(Ah0[ks], bl, a0);
        a1 = MFMA16(Ah1[ks], bh, a1);
        a1 = MFMA16(Al1[ks], bh, a1);
        a1 = MFMA16(Ah1[ks], bl, a1);
      }
      // epilogue: d = sq_j - 2*dot; ascending cg then t, strict < = first-min
      const int j = jb + cg * 16 + lc;
#pragma unroll
      for (int r = 0; r < 4; ++r) {
        float d0 = fmaf(-2.0f, a0[r], sqc[cg]);
        if (j != ig0 + r && d0 < best0[r]) { best0[r] = d0; bidx0[r] = j; }
        float d1 = fmaf(-2.0f, a1[r], sqc[cg]);
        if (j != ig0 + 16 + r && d1 < best1[r]) { best1[r] = d1; bidx1[r] = j; }
      }
    }

    __syncthreads();  // drains my stage (vmcnt 0) + all waves done reading buf
    buf ^= 1;
  }

  // cross-lane argmin over the 16 col-lanes sharing each row; lex (d,j) = first-min
#pragma unroll
  for (int r = 0; r < 4; ++r) {
    float d0 = best0[r], d1 = best1[r];
    int i0 = bidx0[r], i1 = bidx1[r];
#pragma unroll
    for (int off = 1; off < 16; off <<= 1) {
      float od = __shfl_xor(d0, off); int oi = __shfl_xor(i0, off);
      if (od < d0 || (od == d0 && oi < i0)) { d0 = od; i0 = oi; }
      od = __shfl_xor(d1, off); oi = __shfl_xor(i1, off);
      if (od < d1 || (od == d1 && oi < i1)) { d1 = od; i1 = oi; }
    }
    if (lc == 0) {  // rows are wave/lane-quad exclusive
      bestD[slice * NN + ig0 + r] = d0;
      bestI[slice * NN + ig0 + r] = i0;
      bestD[slice * NN + ig0 + 16 + r] = d1;
      bestI[slice * NN + ig0 + 16 + r] = i1;
    }
  }
}

// --- merge 8 slices per row, count label matches ---
__global__ __launch_bounds__(256) void combine_kernel(const float* __restrict__ bestD,
                                                      const int* __restrict__ bestI,
                                                      const int* __restrict__ labels,
                                                      int* __restrict__ count) {
  int r = blockIdx.x * 256 + threadIdx.x;
  float d = bestD[r];
  int i = bestI[r];
#pragma unroll
  for (int s = 1; s < 8; ++s) {
    float ds = bestD[s * NN + r];
    int is = bestI[s * NN + r];
    if (ds < d || (ds == d && is < i)) { d = ds; i = is; }
  }
  bool match = (labels[i] == labels[r]);
  unsigned long long mb = __ballot(match);
  if ((threadIdx.x & 63) == 0) atomicAdd(count, (int)__popcll(mb));
}

__global__ void finalize_kernel(const int* __restrict__ count, float* __restrict__ out) {
  out[0] = (float)(*count) * (1.0f / 16384.0f);
}

extern "C" void kernel_launch(void* const* d_in, const int* in_sizes, int n_in,
                              void* d_out, int out_size, void* d_ws, size_t ws_size,
                              hipStream_t stream) {
  const float* feat = (const float*)d_in[0];
  const int* labels = (const int*)d_in[1];
  float* out = (float*)d_out;
  char* ws = (char*)d_ws;

  int* count = (int*)ws;                              // 4 B
  float* sq = (float*)(ws + 1024);                    // 64 KB
  float* bestD = (float*)(ws + (1 << 19));            // 8*N floats = 512 KB
  int* bestI = (int*)(ws + (1 << 20));                // 8*N ints  = 512 KB
  bf16x8* Ph = (bf16x8*)(ws + (2 << 20));             // 4 MB
  bf16x8* Pl = (bf16x8*)(ws + (6 << 20));             // 4 MB   (total 10 MB)

  hipMemsetAsync(count, 0, sizeof(int), stream);
  sq_kernel<<<NN / 4, 256, 0, stream>>>(feat, sq);
  convert_kernel<<<1024, 256, 0, stream>>>(feat, Ph, Pl);
  nn_mfma<<<512, 512, 0, stream>>>(Ph, Pl, sq, bestD, bestI);
  combine_kernel<<<NN / 256, 256, 0, stream>>>(bestD, bestI, labels, count);
  finalize_kernel<<<1, 1, 0, stream>>>(count, out);
}